// Round 4
// baseline (437.339 us; speedup 1.0000x reference)
//
#include <hip/hip_runtime.h>
#include <stdint.h>

typedef __attribute__((ext_vector_type(8))) short short8;
typedef __attribute__((ext_vector_type(4))) float f32x4;
typedef __attribute__((ext_vector_type(4))) unsigned int u32x4;

#define DIM 768
#define H3 2304
#define SEQ 4096
#define NTOK 16384

__device__ __forceinline__ unsigned short f2bf(float f) {
  union { float f; uint32_t u; } c; c.f = f;
  uint32_t u = c.u;
  u += 0x7FFFu + ((u >> 16) & 1u);   // RNE; inputs are finite
  return (unsigned short)(u >> 16);
}

__device__ __forceinline__ void async_cp16(const void* g, void* l) {
  // global -> LDS direct, 16B per lane. LDS dest must be waveBase + lane*16 (it is).
  __builtin_amdgcn_global_load_lds(
      (__attribute__((address_space(1))) void*)(void*)g,
      (__attribute__((address_space(3))) void*)l, 16, 0, 0);
}

#define MEMFENCE() asm volatile("" ::: "memory")
#define BARRIER() do { MEMFENCE(); __builtin_amdgcn_s_barrier(); MEMFENCE(); } while (0)
#define WAIT_LGK0() do { asm volatile("s_waitcnt lgkmcnt(0)" ::: "memory"); \
                         __builtin_amdgcn_sched_barrier(0); } while (0)
#define WAIT_VMCNT(n) asm volatile("s_waitcnt vmcnt(" #n ")" ::: "memory")

// ---- legacy 128-tile NT GEMM core (kept for k_qkv only) ----
template<int JN>
__device__ __forceinline__ void gemm_nt64_t(
    const unsigned short* __restrict__ A, const unsigned short* __restrict__ B,
    int K, int ldA, int ldB,
    unsigned short* As, unsigned short* Bs, f32x4 acc[4][JN])
{
  const int tid = threadIdx.x, lane = tid & 63, wid = tid >> 6;
  const int wm = (wid & 1) << 6, wn = (wid >> 1) * (JN * 16);
  const int lr = lane & 15, q = lane >> 4;

#pragma unroll
  for (int i = 0; i < 4; ++i)
#pragma unroll
    for (int j = 0; j < JN; ++j)
      acc[i][j] = (f32x4){0.f, 0.f, 0.f, 0.f};

  const unsigned short* gA[4];
  const unsigned short* gB[JN];
#pragma unroll
  for (int t = 0; t < 4; ++t) {
    const int c = tid + 256 * t;
    const int row = c >> 3, sc = c & 7;
    gA[t] = A + (size_t)row * ldA + (((sc ^ (row & 7)) << 3));
  }
#pragma unroll
  for (int t = 0; t < JN; ++t) {
    const int c = tid + 256 * t;
    const int row = c >> 3, sc = c & 7;
    gB[t] = B + (size_t)row * ldB + (((sc ^ (row & 7)) << 3));
  }

  for (int k0 = 0; k0 < K; k0 += 64) {
#pragma unroll
    for (int t = 0; t < 4; ++t)
      async_cp16(gA[t] + k0, As + (tid + 256 * t) * 8);
#pragma unroll
    for (int t = 0; t < JN; ++t)
      async_cp16(gB[t] + k0, Bs + (tid + 256 * t) * 8);
    __syncthreads();

    short8 af[4][2], bfr[JN][2];
#pragma unroll
    for (int i = 0; i < 4; ++i) {
      const int ra = wm + i * 16 + lr;
#pragma unroll
      for (int s2 = 0; s2 < 2; ++s2)
        af[i][s2] = *(const short8*)(As + ra * 64 + (((s2 * 4 + q) ^ (ra & 7)) << 3));
    }
#pragma unroll
    for (int j = 0; j < JN; ++j) {
      const int rb = wn + j * 16 + lr;
#pragma unroll
      for (int s2 = 0; s2 < 2; ++s2)
        bfr[j][s2] = *(const short8*)(Bs + rb * 64 + (((s2 * 4 + q) ^ (rb & 7)) << 3));
    }
#pragma unroll
    for (int s2 = 0; s2 < 2; ++s2)
#pragma unroll
      for (int i = 0; i < 4; ++i)
#pragma unroll
        for (int j = 0; j < JN; ++j)
          acc[i][j] = __builtin_amdgcn_mfma_f32_16x16x32_bf16(af[i][s2], bfr[j][s2], acc[i][j], 0, 0, 0);
    __syncthreads();
  }
}

// ---- R10: 256-wide 4-phase/K-tile counted-vmcnt NT GEMM core (T3+T4+T5) ----
// Measured R11: verified, k_scores 143 µs, MfmaUtil 30.8, FETCH 147.6 MB
// (3x ideal 50 MB) -> latency-bound on evicted panels, NOT schedule-bound.
// Core unchanged (R13 = R12's nt-store mechanism with compile fix).
template<int JN>
__device__ __forceinline__ void gemm256_nt(
    const unsigned short* __restrict__ A, const unsigned short* __restrict__ B,
    int K, int ldA, int ldB, unsigned short* lds, f32x4 acc[8][JN])
{
  const int tid = threadIdx.x, lane = tid & 63, wid = tid >> 6;
  const int wr = wid >> 2, wc = wid & 3;
  const int lr = lane & 15, q = lane >> 4;

  unsigned short* const As0 = lds;
  unsigned short* const As1 = lds + 16384;
  unsigned short* const Bs0 = lds + 32768;
  unsigned short* const Bs1 = lds + 32768 + JN * 4096;

#pragma unroll
  for (int i = 0; i < 8; ++i)
#pragma unroll
    for (int j = 0; j < JN; ++j)
      acc[i][j] = (f32x4){0.f, 0.f, 0.f, 0.f};

  const unsigned short* gA[4];
  const unsigned short* gB[JN];
#pragma unroll
  for (int t = 0; t < 4; ++t) {
    const int c = tid + 512 * t, row = c >> 3, sc = c & 7;
    gA[t] = A + (size_t)row * ldA + ((sc ^ (row & 7)) << 3);
  }
#pragma unroll
  for (int t = 0; t < JN; ++t) {
    const int c = tid + 512 * t, row = c >> 3, sc = c & 7;
    gB[t] = B + (size_t)row * ldB + ((sc ^ (row & 7)) << 3);
  }

  const int nt = K >> 6;

  // prologue: tile0 (A,B) -> buf0; tile1 A -> buf1. vmcnt(4): tile0 complete,
  // tile1's 4 A-loads stay in flight (matches steady-state ledger at ph1).
#pragma unroll
  for (int t = 0; t < 4; ++t) async_cp16(gA[t], As0 + (tid + 512 * t) * 8);
#pragma unroll
  for (int t = 0; t < JN; ++t) async_cp16(gB[t], Bs0 + (tid + 512 * t) * 8);
  const int k1 = (nt > 1) ? 64 : 0;
#pragma unroll
  for (int t = 0; t < 4; ++t) async_cp16(gA[t] + k1, As1 + (tid + 512 * t) * 8);
  WAIT_VMCNT(4);
  BARRIER();

  short8 af[8], bf01[2], bfr[(JN > 2) ? (JN - 2) : 1];

#pragma unroll 2
  for (int t = 0; t < nt; ++t) {
    const int p = t & 1;
    const unsigned short* const Asp = p ? As1 : As0;
    const unsigned short* const Bsp = p ? Bs1 : Bs0;
    unsigned short* const Bsn = p ? Bs0 : Bs1;           // B stage: tile t+1
    unsigned short* const Asn = p ? As1 : As0;           // A stage: tile t+2 (same buf)
    const int kB = ((t + 1 < nt) ? t + 1 : nt - 1) << 6; // clamped tail re-load keeps
    const int kA = ((t + 2 < nt) ? t + 2 : nt - 1) << 6; // the vmcnt ledger uniform

    // ---- phase 1 ----
    async_cp16(gB[0] + kB, Bsn + tid * 8);
    async_cp16(gB[1] + kB, Bsn + (tid + 512) * 8);
#pragma unroll
    for (int i = 0; i < 8; ++i) {
      const int ra = wr * 128 + i * 16 + lr;
      af[i] = *(const short8*)(Asp + ra * 64 + ((q ^ (ra & 7)) << 3));
    }
#pragma unroll
    for (int j = 0; j < 2; ++j) {
      const int rb = wc * (JN * 16) + j * 16 + lr;
      bf01[j] = *(const short8*)(Bsp + rb * 64 + ((q ^ (rb & 7)) << 3));
    }
    BARRIER();
    WAIT_LGK0();
    __builtin_amdgcn_s_setprio(1);
#pragma unroll
    for (int i = 0; i < 8; ++i)
#pragma unroll
      for (int j = 0; j < 2; ++j)
        acc[i][j] = __builtin_amdgcn_mfma_f32_16x16x32_bf16(af[i], bf01[j], acc[i][j], 0, 0, 0);
    __builtin_amdgcn_s_setprio(0);
    BARRIER();

    // ---- phase 2 ----
#pragma unroll
    for (int u = 2; u < JN; ++u)
      async_cp16(gB[u] + kB, Bsn + (tid + 512 * u) * 8);
#pragma unroll
    for (int j = 2; j < JN; ++j) {
      const int rb = wc * (JN * 16) + j * 16 + lr;
      bfr[j - 2] = *(const short8*)(Bsp + rb * 64 + ((q ^ (rb & 7)) << 3));
    }
    BARRIER();
    WAIT_LGK0();
    __builtin_amdgcn_s_setprio(1);
#pragma unroll
    for (int i = 0; i < 8; ++i)
#pragma unroll
      for (int j = 2; j < JN; ++j)
        acc[i][j] = __builtin_amdgcn_mfma_f32_16x16x32_bf16(af[i], bfr[j - 2], acc[i][j], 0, 0, 0);
    __builtin_amdgcn_s_setprio(0);
    BARRIER();

    // ---- phase 3 ----
#pragma unroll
    for (int i = 0; i < 8; ++i) {
      const int ra = wr * 128 + i * 16 + lr;
      af[i] = *(const short8*)(Asp + ra * 64 + (((4 + q) ^ (ra & 7)) << 3));
    }
#pragma unroll
    for (int j = 0; j < 2; ++j) {
      const int rb = wc * (JN * 16) + j * 16 + lr;
      bf01[j] = *(const short8*)(Bsp + rb * 64 + (((4 + q) ^ (rb & 7)) << 3));
    }
    BARRIER();
    WAIT_LGK0();
    __builtin_amdgcn_s_setprio(1);
#pragma unroll
    for (int i = 0; i < 8; ++i)
#pragma unroll
      for (int j = 0; j < 2; ++j)
        acc[i][j] = __builtin_amdgcn_mfma_f32_16x16x32_bf16(af[i], bf01[j], acc[i][j], 0, 0, 0);
    __builtin_amdgcn_s_setprio(0);
    BARRIER();

    // ---- phase 4 ----
#pragma unroll
    for (int u = 0; u < 4; ++u)
      async_cp16(gA[u] + kA, Asn + (tid + 512 * u) * 8);
#pragma unroll
    for (int j = 2; j < JN; ++j) {
      const int rb = wc * (JN * 16) + j * 16 + lr;
      bfr[j - 2] = *(const short8*)(Bsp + rb * 64 + (((4 + q) ^ (rb & 7)) << 3));
    }
    BARRIER();
    WAIT_LGK0();
    __builtin_amdgcn_s_setprio(1);
#pragma unroll
    for (int i = 0; i < 8; ++i)
#pragma unroll
      for (int j = 2; j < JN; ++j)
        acc[i][j] = __builtin_amdgcn_mfma_f32_16x16x32_bf16(af[i], bfr[j - 2], acc[i][j], 0, 0, 0);
    __builtin_amdgcn_s_setprio(0);
    WAIT_VMCNT(4);
    BARRIER();
  }
  // drain clamped tail prefetches before LDS reuse / kernel exit (in-flight
  // DMA into freed LDS would corrupt a successor workgroup).
  WAIT_VMCNT(0);
  BARRIER();
}

// ---- kernel 0a: fp32 -> bf16 bulk convert (x) ----
// x is read exactly once -> nontemporal load keeps L2/L3 clean for x_bf.
// NOTE: __builtin_nontemporal_* needs ext_vector types, not HIP_vector_type.
__global__ __launch_bounds__(256) void k_cvt(const float* __restrict__ in,
                                             unsigned short* __restrict__ o) {
  int i = blockIdx.x * 256 + threadIdx.x;
  f32x4 f = __builtin_nontemporal_load(((const f32x4*)in) + i);
  ushort4 u;
  u.x = f2bf(f.x); u.y = f2bf(f.y); u.z = f2bf(f.z); u.w = f2bf(f.w);
  ((ushort4*)o)[i] = u;
}

// ---- kernel 0b: W [768,2304] fp32 -> Wt [2304,768] bf16 ----
__global__ __launch_bounds__(256) void k_transpose(const float* __restrict__ W,
                                                   unsigned short* __restrict__ Wt) {
  __shared__ float tile[32][33];
  const int bc = blockIdx.x * 32;
  const int br = blockIdx.y * 32;
  const int tx = threadIdx.x & 31, ty = threadIdx.x >> 5;
#pragma unroll
  for (int i = 0; i < 32; i += 8)
    tile[ty + i][tx] = W[(size_t)(br + ty + i) * H3 + bc + tx];
  __syncthreads();
#pragma unroll
  for (int i = 0; i < 32; i += 8)
    Wt[(size_t)(bc + ty + i) * DIM + br + tx] = f2bf(tile[tx][ty + i]);
}

// ---- kernel 1: qkv = x @ Wt^T + b ; q scaled, k plain, v transposed ----
__global__ __launch_bounds__(256) void k_qkv(
    const unsigned short* __restrict__ xbf, const unsigned short* __restrict__ Wt,
    const float* __restrict__ bias,
    unsigned short* __restrict__ qb, unsigned short* __restrict__ kb,
    unsigned short* __restrict__ vT)
{
  __shared__ unsigned short As[128 * 64];
  __shared__ unsigned short Bs[128 * 64];
  f32x4 acc[4][4];
  const int g = blockIdx.x;
  const int xcd = g & 7, slot = g >> 3;        // slot in [0,288)
  const int tn = slot % 18, grp = slot / 18;   // grp in [0,16)
  const int tm = xcd + 8 * grp;                // row-strip in [0,128)
  gemm_nt64_t<4>(xbf + (size_t)(tm * 128) * DIM, Wt + (size_t)(tn * 128) * DIM,
                 DIM, DIM, DIM, As, Bs, acc);

  const int tid = threadIdx.x, lane = tid & 63, wid = tid >> 6;
  const int wm = (wid & 1) << 6, wn = (wid >> 1) << 6;
  const float scale = 0.036084391824351615f;  // 1/sqrt(768)
#pragma unroll
  for (int i = 0; i < 4; ++i) {
#pragma unroll
    for (int j = 0; j < 4; ++j) {
      const int col  = tn * 128 + wn + j * 16 + (lane & 15);
      const int row0 = tm * 128 + wm + i * 16 + ((lane >> 4) << 2);
      const float bc = bias[col];
#pragma unroll
      for (int r = 0; r < 4; ++r) {
        const int row = row0 + r;
        const float v = acc[i][j][r] + bc;
        if (col < 768) {
          qb[(size_t)row * DIM + col] = f2bf(v * scale);
        } else if (col < 1536) {
          kb[(size_t)row * DIM + (col - 768)] = f2bf(v);
        } else {
          const int b = row >> 12, n = row & 4095;
          vT[((size_t)b * DIM + (col - 1536)) * SEQ + n] = f2bf(v);
        }
      }
    }
  }
}

// ---- kernel 2 (R13): P'[b] = exp(q@k^T), 256x256 tiles, nt S-store ----
// R11 measured: 143 µs, FETCH 147.6 MB vs ideal 50 MB. The 4 MB/round/XCD
// S-write stream evicts the reused q/k panels (4.7 MB working set vs 4 MB L2)
// -> HBM re-fetch + latency stalls at the per-tile vmcnt(4). Fix: store S
// nontemporal (evict-first in L2); q-strips then persist across all 4 rounds
// (grid mapping already repeats the same 8 strips per XCD every round).
__global__ __launch_bounds__(512, 2) void k_scores(
    const unsigned short* __restrict__ qb, const unsigned short* __restrict__ kb,
    unsigned short* __restrict__ S, float* __restrict__ lpart)
{
  __shared__ unsigned short lds[65536];        // 128 KB
  f32x4 acc[8][4];
  const int g = blockIdx.x;
  const int xcd = g & 7, slot = g >> 3;        // slot in [0,128)
  const int grp = slot & 7, tn = slot >> 3;    // tn in [0,16)
  const int s  = xcd + 8 * grp;                // strip in [0,64)
  const int ty = s & 15, b = s >> 4;
  gemm256_nt<4>(qb + ((size_t)b * SEQ + ty * 256) * DIM,
                kb + ((size_t)b * SEQ + tn * 256) * DIM,
                DIM, DIM, DIM, lds, acc);

  const int tid = threadIdx.x, lane = tid & 63, wid = tid >> 6;
  const int wr = wid >> 2, wc = wid & 3;
  const int lr = lane & 15, q = lane >> 4;

  float rs[8][4];
#pragma unroll
  for (int i = 0; i < 8; ++i)
#pragma unroll
    for (int r = 0; r < 4; ++r) rs[i][r] = 0.f;

#pragma unroll
  for (int i = 0; i < 8; ++i)
#pragma unroll
    for (int j = 0; j < 4; ++j) {
      const int col = wc * 64 + j * 16 + lr;
#pragma unroll
      for (int r = 0; r < 4; ++r) {
        const int row = wr * 128 + i * 16 + (q << 2) + r;
        const float e = __expf(acc[i][j][r]);
        lds[row * 256 + (((col >> 3) ^ (((row >> 2) & 3) << 1)) << 3) + (col & 7)] = f2bf(e);
        rs[i][r] += e;
      }
    }

  float* lp = lpart + (size_t)(tn * 4 + wc) * NTOK;
  const int lbase = b * SEQ + ty * 256 + wr * 128 + (q << 2);
#pragma unroll
  for (int i = 0; i < 8; ++i)
#pragma unroll
    for (int r = 0; r < 4; ++r) {
      float v = rs[i][r];
      v += __shfl_xor(v, 1); v += __shfl_xor(v, 2);
      v += __shfl_xor(v, 4); v += __shfl_xor(v, 8);
      if (lr == 0) lp[lbase + i * 16 + r] = v;
    }
  __syncthreads();
  unsigned short* Sb = S + (size_t)b * SEQ * SEQ;
  const int rL = tid >> 5, cc = tid & 31;
#pragma unroll
  for (int pp = 0; pp < 16; ++pp) {
    const int row = pp * 16 + rL;
    const int pos = cc ^ (((row >> 2) & 3) << 1);
    const u32x4 vv = *(const u32x4*)(lds + row * 256 + pos * 8);
    __builtin_nontemporal_store(
        vv, (u32x4*)(Sb + (size_t)(ty * 256 + row) * SEQ + tn * 256 + cc * 8));
  }
}

// ---- kernel 2b: fold 64 partials per row -> reciprocal row sum ----
__global__ __launch_bounds__(256) void k_lred(const float* __restrict__ lpart,
                                              float* __restrict__ lsum) {
  const int tid = threadIdx.x;
  const int row = blockIdx.x * 64 + (tid >> 2);
  const int part = tid & 3;
  float s = 0.f;
#pragma unroll
  for (int t = 0; t < 16; ++t)
    s += lpart[(size_t)(part * 16 + t) * NTOK + row];
  s += __shfl_xor(s, 1);
  s += __shfl_xor(s, 2);
  if (part == 0) lsum[row] = 1.0f / s;
}

// ---- kernel 3 (R13): out[b] = (P'[b] @ vT[b]^T) * lsum, nt out-store ----
// Same mechanism: out (201 MB fp32, never re-read) streamed nontemporal so
// the reused vT panels (~3 MB/XCD) stay L2-resident against the write stream.
__global__ __launch_bounds__(512, 2) void k_pv(
    const unsigned short* __restrict__ P, const unsigned short* __restrict__ vT,
    const float* __restrict__ lsum, float* __restrict__ out)
{
  __shared__ unsigned short lds[57344];        // 112 KB
  f32x4 acc[8][3];
  const int g = blockIdx.x;                    // flat grid 256
  const int xcd = g & 7, s = g >> 3;           // s in [0,32)
  const int combo = xcd * 2 + (s & 1);         // [0,16)
  const int b = combo >> 2, tn = combo & 3;
  const int tm = s >> 1;                       // [0,16)
  gemm256_nt<3>(P + (size_t)b * SEQ * SEQ + (size_t)(tm * 256) * SEQ,
                vT + (size_t)b * DIM * SEQ + (size_t)(tn * 192) * SEQ,
                SEQ, SEQ, SEQ, lds, acc);

  const int tid = threadIdx.x, lane = tid & 63, wid = tid >> 6;
  const int wr = wid >> 2, wc = wid & 3;
  const int lr = lane & 15, q = lane >> 4;
  const int lbase = b * SEQ + tm * 256 + wr * 128 + (q << 2);
  float inv[8][4];
#pragma unroll
  for (int i = 0; i < 8; ++i)
#pragma unroll
    for (int r = 0; r < 4; ++r) inv[i][r] = lsum[lbase + i * 16 + r];
  float* ob = out + (size_t)b * SEQ * DIM;
#pragma unroll
  for (int i = 0; i < 8; ++i)
#pragma unroll
    for (int j = 0; j < 3; ++j) {
      const int col  = tn * 192 + wc * 48 + j * 16 + lr;
      const int row0 = tm * 256 + wr * 128 + i * 16 + (q << 2);
#pragma unroll
      for (int r = 0; r < 4; ++r)
        __builtin_nontemporal_store(acc[i][j][r] * inv[i][r],
                                    &ob[(size_t)(row0 + r) * DIM + col]);
    }
}

extern "C" void kernel_launch(void* const* d_in, const int* in_sizes, int n_in,
                              void* d_out, int out_size, void* d_ws, size_t ws_size,
                              hipStream_t stream) {
  const float* x    = (const float*)d_in[0];
  const float* W    = (const float*)d_in[1];
  const float* bias = (const float*)d_in[2];
  float* out = (float*)d_out;

  char* w = (char*)d_ws;
  unsigned short* x_bf = (unsigned short*)(w);
  unsigned short* Wt   = (unsigned short*)(w + 25165824);
  unsigned short* qb   = (unsigned short*)(w + 28704768);
  unsigned short* kb   = (unsigned short*)(w + 53870592);
  unsigned short* vT   = (unsigned short*)(w + 79036416);
  unsigned short* S    = (unsigned short*)(w + 104202240);
  // lpart (4 MB) + lsum (64 KB) reuse the x_bf region (dead after k_qkv)
  float* lpart = (float*)(w);
  float* lsum  = (float*)(w + 4194304);

  k_cvt      <<<12288, 256, 0, stream>>>(x, x_bf);
  k_transpose<<<dim3(72, 24), 256, 0, stream>>>(W, Wt);
  k_qkv      <<<2304, 256, 0, stream>>>(x_bf, Wt, bias, qb, kb, vT);
  k_scores   <<<1024, 512, 0, stream>>>(qb, kb, S, lpart);
  k_lred     <<<256, 256, 0, stream>>>(lpart, lsum);
  k_pv       <<<256, 512, 0, stream>>>(S, vT, lsum, out);
}

// Round 5
// 426.249 us; speedup vs baseline: 1.0260x; 1.0260x over previous
//
#include <hip/hip_runtime.h>
#include <stdint.h>

typedef __attribute__((ext_vector_type(8))) short short8;
typedef __attribute__((ext_vector_type(4))) float f32x4;

#define DIM 768
#define H3 2304
#define SEQ 4096
#define NTOK 16384

__device__ __forceinline__ unsigned short f2bf(float f) {
  union { float f; uint32_t u; } c; c.f = f;
  uint32_t u = c.u;
  u += 0x7FFFu + ((u >> 16) & 1u);   // RNE; inputs are finite
  return (unsigned short)(u >> 16);
}

__device__ __forceinline__ void async_cp16(const void* g, void* l) {
  // global -> LDS direct, 16B per lane. LDS dest must be waveBase + lane*16 (it is).
  __builtin_amdgcn_global_load_lds(
      (__attribute__((address_space(1))) void*)(void*)g,
      (__attribute__((address_space(3))) void*)l, 16, 0, 0);
}

#define MEMFENCE() asm volatile("" ::: "memory")
#define BARRIER() do { MEMFENCE(); __builtin_amdgcn_s_barrier(); MEMFENCE(); } while (0)
#define WAIT_LGK0() do { asm volatile("s_waitcnt lgkmcnt(0)" ::: "memory"); \
                         __builtin_amdgcn_sched_barrier(0); } while (0)
#define WAIT_VMCNT(n) asm volatile("s_waitcnt vmcnt(" #n ")" ::: "memory")

// ---- legacy 128-tile NT GEMM core (kept for k_qkv only) ----
template<int JN>
__device__ __forceinline__ void gemm_nt64_t(
    const unsigned short* __restrict__ A, const unsigned short* __restrict__ B,
    int K, int ldA, int ldB,
    unsigned short* As, unsigned short* Bs, f32x4 acc[4][JN])
{
  const int tid = threadIdx.x, lane = tid & 63, wid = tid >> 6;
  const int wm = (wid & 1) << 6, wn = (wid >> 1) * (JN * 16);
  const int lr = lane & 15, q = lane >> 4;

#pragma unroll
  for (int i = 0; i < 4; ++i)
#pragma unroll
    for (int j = 0; j < JN; ++j)
      acc[i][j] = (f32x4){0.f, 0.f, 0.f, 0.f};

  const unsigned short* gA[4];
  const unsigned short* gB[JN];
#pragma unroll
  for (int t = 0; t < 4; ++t) {
    const int c = tid + 256 * t;
    const int row = c >> 3, sc = c & 7;
    gA[t] = A + (size_t)row * ldA + (((sc ^ (row & 7)) << 3));
  }
#pragma unroll
  for (int t = 0; t < JN; ++t) {
    const int c = tid + 256 * t;
    const int row = c >> 3, sc = c & 7;
    gB[t] = B + (size_t)row * ldB + (((sc ^ (row & 7)) << 3));
  }

  for (int k0 = 0; k0 < K; k0 += 64) {
#pragma unroll
    for (int t = 0; t < 4; ++t)
      async_cp16(gA[t] + k0, As + (tid + 256 * t) * 8);
#pragma unroll
    for (int t = 0; t < JN; ++t)
      async_cp16(gB[t] + k0, Bs + (tid + 256 * t) * 8);
    __syncthreads();

    short8 af[4][2], bfr[JN][2];
#pragma unroll
    for (int i = 0; i < 4; ++i) {
      const int ra = wm + i * 16 + lr;
#pragma unroll
      for (int s2 = 0; s2 < 2; ++s2)
        af[i][s2] = *(const short8*)(As + ra * 64 + (((s2 * 4 + q) ^ (ra & 7)) << 3));
    }
#pragma unroll
    for (int j = 0; j < JN; ++j) {
      const int rb = wn + j * 16 + lr;
#pragma unroll
      for (int s2 = 0; s2 < 2; ++s2)
        bfr[j][s2] = *(const short8*)(Bs + rb * 64 + (((s2 * 4 + q) ^ (rb & 7)) << 3));
    }
#pragma unroll
    for (int s2 = 0; s2 < 2; ++s2)
#pragma unroll
      for (int i = 0; i < 4; ++i)
#pragma unroll
        for (int j = 0; j < JN; ++j)
          acc[i][j] = __builtin_amdgcn_mfma_f32_16x16x32_bf16(af[i][s2], bfr[j][s2], acc[i][j], 0, 0, 0);
    __syncthreads();
  }
}

// ---- R10: 256-wide 4-phase/K-tile counted-vmcnt NT GEMM core (T3+T4+T5) ----
// R11 measured: k_scores 143-146 µs, MfmaUtil 29, FETCH 147.6 MB (3x ideal).
// R13 falsified write-eviction (nt-store: FETCH unchanged). R14 theory:
// resident working set 9 MB/XCD > 4 MB L2 (cross-batch strips) -> L2 thrash
// -> long-latency B loads under a 3.5-phase cover -> vmcnt(4) stalls.
// Core unchanged; fix is the grid->(b,ty,tn) mapping in k_scores.
template<int JN>
__device__ __forceinline__ void gemm256_nt(
    const unsigned short* __restrict__ A, const unsigned short* __restrict__ B,
    int K, int ldA, int ldB, unsigned short* lds, f32x4 acc[8][JN])
{
  const int tid = threadIdx.x, lane = tid & 63, wid = tid >> 6;
  const int wr = wid >> 2, wc = wid & 3;
  const int lr = lane & 15, q = lane >> 4;

  unsigned short* const As0 = lds;
  unsigned short* const As1 = lds + 16384;
  unsigned short* const Bs0 = lds + 32768;
  unsigned short* const Bs1 = lds + 32768 + JN * 4096;

#pragma unroll
  for (int i = 0; i < 8; ++i)
#pragma unroll
    for (int j = 0; j < JN; ++j)
      acc[i][j] = (f32x4){0.f, 0.f, 0.f, 0.f};

  const unsigned short* gA[4];
  const unsigned short* gB[JN];
#pragma unroll
  for (int t = 0; t < 4; ++t) {
    const int c = tid + 512 * t, row = c >> 3, sc = c & 7;
    gA[t] = A + (size_t)row * ldA + ((sc ^ (row & 7)) << 3);
  }
#pragma unroll
  for (int t = 0; t < JN; ++t) {
    const int c = tid + 512 * t, row = c >> 3, sc = c & 7;
    gB[t] = B + (size_t)row * ldB + ((sc ^ (row & 7)) << 3);
  }

  const int nt = K >> 6;

  // prologue: tile0 (A,B) -> buf0; tile1 A -> buf1. vmcnt(4): tile0 complete,
  // tile1's 4 A-loads stay in flight (matches steady-state ledger at ph1).
#pragma unroll
  for (int t = 0; t < 4; ++t) async_cp16(gA[t], As0 + (tid + 512 * t) * 8);
#pragma unroll
  for (int t = 0; t < JN; ++t) async_cp16(gB[t], Bs0 + (tid + 512 * t) * 8);
  const int k1 = (nt > 1) ? 64 : 0;
#pragma unroll
  for (int t = 0; t < 4; ++t) async_cp16(gA[t] + k1, As1 + (tid + 512 * t) * 8);
  WAIT_VMCNT(4);
  BARRIER();

  short8 af[8], bf01[2], bfr[(JN > 2) ? (JN - 2) : 1];

#pragma unroll 2
  for (int t = 0; t < nt; ++t) {
    const int p = t & 1;
    const unsigned short* const Asp = p ? As1 : As0;
    const unsigned short* const Bsp = p ? Bs1 : Bs0;
    unsigned short* const Bsn = p ? Bs0 : Bs1;           // B stage: tile t+1
    unsigned short* const Asn = p ? As1 : As0;           // A stage: tile t+2 (same buf)
    const int kB = ((t + 1 < nt) ? t + 1 : nt - 1) << 6; // clamped tail re-load keeps
    const int kA = ((t + 2 < nt) ? t + 2 : nt - 1) << 6; // the vmcnt ledger uniform

    // ---- phase 1 ----
    async_cp16(gB[0] + kB, Bsn + tid * 8);
    async_cp16(gB[1] + kB, Bsn + (tid + 512) * 8);
#pragma unroll
    for (int i = 0; i < 8; ++i) {
      const int ra = wr * 128 + i * 16 + lr;
      af[i] = *(const short8*)(Asp + ra * 64 + ((q ^ (ra & 7)) << 3));
    }
#pragma unroll
    for (int j = 0; j < 2; ++j) {
      const int rb = wc * (JN * 16) + j * 16 + lr;
      bf01[j] = *(const short8*)(Bsp + rb * 64 + ((q ^ (rb & 7)) << 3));
    }
    BARRIER();
    WAIT_LGK0();
    __builtin_amdgcn_s_setprio(1);
#pragma unroll
    for (int i = 0; i < 8; ++i)
#pragma unroll
      for (int j = 0; j < 2; ++j)
        acc[i][j] = __builtin_amdgcn_mfma_f32_16x16x32_bf16(af[i], bf01[j], acc[i][j], 0, 0, 0);
    __builtin_amdgcn_s_setprio(0);
    BARRIER();

    // ---- phase 2 ----
#pragma unroll
    for (int u = 2; u < JN; ++u)
      async_cp16(gB[u] + kB, Bsn + (tid + 512 * u) * 8);
#pragma unroll
    for (int j = 2; j < JN; ++j) {
      const int rb = wc * (JN * 16) + j * 16 + lr;
      bfr[j - 2] = *(const short8*)(Bsp + rb * 64 + ((q ^ (rb & 7)) << 3));
    }
    BARRIER();
    WAIT_LGK0();
    __builtin_amdgcn_s_setprio(1);
#pragma unroll
    for (int i = 0; i < 8; ++i)
#pragma unroll
      for (int j = 2; j < JN; ++j)
        acc[i][j] = __builtin_amdgcn_mfma_f32_16x16x32_bf16(af[i], bfr[j - 2], acc[i][j], 0, 0, 0);
    __builtin_amdgcn_s_setprio(0);
    BARRIER();

    // ---- phase 3 ----
#pragma unroll
    for (int i = 0; i < 8; ++i) {
      const int ra = wr * 128 + i * 16 + lr;
      af[i] = *(const short8*)(Asp + ra * 64 + (((4 + q) ^ (ra & 7)) << 3));
    }
#pragma unroll
    for (int j = 0; j < 2; ++j) {
      const int rb = wc * (JN * 16) + j * 16 + lr;
      bf01[j] = *(const short8*)(Bsp + rb * 64 + (((4 + q) ^ (rb & 7)) << 3));
    }
    BARRIER();
    WAIT_LGK0();
    __builtin_amdgcn_s_setprio(1);
#pragma unroll
    for (int i = 0; i < 8; ++i)
#pragma unroll
      for (int j = 0; j < 2; ++j)
        acc[i][j] = __builtin_amdgcn_mfma_f32_16x16x32_bf16(af[i], bf01[j], acc[i][j], 0, 0, 0);
    __builtin_amdgcn_s_setprio(0);
    BARRIER();

    // ---- phase 4 ----
#pragma unroll
    for (int u = 0; u < 4; ++u)
      async_cp16(gA[u] + kA, Asn + (tid + 512 * u) * 8);
#pragma unroll
    for (int j = 2; j < JN; ++j) {
      const int rb = wc * (JN * 16) + j * 16 + lr;
      bfr[j - 2] = *(const short8*)(Bsp + rb * 64 + (((4 + q) ^ (rb & 7)) << 3));
    }
    BARRIER();
    WAIT_LGK0();
    __builtin_amdgcn_s_setprio(1);
#pragma unroll
    for (int i = 0; i < 8; ++i)
#pragma unroll
      for (int j = 2; j < JN; ++j)
        acc[i][j] = __builtin_amdgcn_mfma_f32_16x16x32_bf16(af[i], bfr[j - 2], acc[i][j], 0, 0, 0);
    __builtin_amdgcn_s_setprio(0);
    WAIT_VMCNT(4);
    BARRIER();
  }
  // drain clamped tail prefetches before LDS reuse / kernel exit (in-flight
  // DMA into freed LDS would corrupt a successor workgroup).
  WAIT_VMCNT(0);
  BARRIER();
}

// ---- kernel 0a: fp32 -> bf16 bulk convert (x) ---- (nt reverted: R13 null)
__global__ __launch_bounds__(256) void k_cvt(const float* __restrict__ in,
                                             unsigned short* __restrict__ o) {
  int i = blockIdx.x * 256 + threadIdx.x;
  float4 f = ((const float4*)in)[i];
  ushort4 u;
  u.x = f2bf(f.x); u.y = f2bf(f.y); u.z = f2bf(f.z); u.w = f2bf(f.w);
  ((ushort4*)o)[i] = u;
}

// ---- kernel 0b: W [768,2304] fp32 -> Wt [2304,768] bf16 ----
__global__ __launch_bounds__(256) void k_transpose(const float* __restrict__ W,
                                                   unsigned short* __restrict__ Wt) {
  __shared__ float tile[32][33];
  const int bc = blockIdx.x * 32;
  const int br = blockIdx.y * 32;
  const int tx = threadIdx.x & 31, ty = threadIdx.x >> 5;
#pragma unroll
  for (int i = 0; i < 32; i += 8)
    tile[ty + i][tx] = W[(size_t)(br + ty + i) * H3 + bc + tx];
  __syncthreads();
#pragma unroll
  for (int i = 0; i < 32; i += 8)
    Wt[(size_t)(bc + ty + i) * DIM + br + tx] = f2bf(tile[tx][ty + i]);
}

// ---- kernel 1: qkv = x @ Wt^T + b ; q scaled, k plain, v transposed ----
// Per-XCD working set (2 x-strips + full Wt) ~3.9 MB: already L2-fits. Leave.
__global__ __launch_bounds__(256) void k_qkv(
    const unsigned short* __restrict__ xbf, const unsigned short* __restrict__ Wt,
    const float* __restrict__ bias,
    unsigned short* __restrict__ qb, unsigned short* __restrict__ kb,
    unsigned short* __restrict__ vT)
{
  __shared__ unsigned short As[128 * 64];
  __shared__ unsigned short Bs[128 * 64];
  f32x4 acc[4][4];
  const int g = blockIdx.x;
  const int xcd = g & 7, slot = g >> 3;        // slot in [0,288)
  const int tn = slot % 18, grp = slot / 18;   // grp in [0,16)
  const int tm = xcd + 8 * grp;                // row-strip in [0,128)
  gemm_nt64_t<4>(xbf + (size_t)(tm * 128) * DIM, Wt + (size_t)(tn * 128) * DIM,
                 DIM, DIM, DIM, As, Bs, acc);

  const int tid = threadIdx.x, lane = tid & 63, wid = tid >> 6;
  const int wm = (wid & 1) << 6, wn = (wid >> 1) << 6;
  const float scale = 0.036084391824351615f;  // 1/sqrt(768)
#pragma unroll
  for (int i = 0; i < 4; ++i) {
#pragma unroll
    for (int j = 0; j < 4; ++j) {
      const int col  = tn * 128 + wn + j * 16 + (lane & 15);
      const int row0 = tm * 128 + wm + i * 16 + ((lane >> 4) << 2);
      const float bc = bias[col];
#pragma unroll
      for (int r = 0; r < 4; ++r) {
        const int row = row0 + r;
        const float v = acc[i][j][r] + bc;
        if (col < 768) {
          qb[(size_t)row * DIM + col] = f2bf(v * scale);
        } else if (col < 1536) {
          kb[(size_t)row * DIM + (col - 768)] = f2bf(v);
        } else {
          const int b = row >> 12, n = row & 4095;
          vT[((size_t)b * DIM + (col - 1536)) * SEQ + n] = f2bf(v);
        }
      }
    }
  }
}

// ---- kernel 2 (R14): P'[b] = exp(q@k^T), batch-per-XCD grid remap ----
// Old mapping: XCD's 32 resident blocks spanned all 4 batches -> 16 k-panels
// (6 MB) + 8 q-strips (3 MB) = 9 MB > 4 MB L2 -> thrash (FETCH 147.6 MB).
// New: b = xcd>>1 (2 XCDs/batch), ty = 2*grp+(xcd&1), tn slowest. Resident
// set = 8 same-batch q-strips (3 MB) + 4 same-batch k-panels (1.5 MB) =
// 4.5 MB; q persists across all 4 tn-rounds; each k-panel touched by only
// 2 XCDs. Bijective (4x16x16 = 1024). Arithmetic per (b,ty,tn) unchanged.
__global__ __launch_bounds__(512, 2) void k_scores(
    const unsigned short* __restrict__ qb, const unsigned short* __restrict__ kb,
    unsigned short* __restrict__ S, float* __restrict__ lpart)
{
  __shared__ unsigned short lds[65536];        // 128 KB
  f32x4 acc[8][4];
  const int g = blockIdx.x;
  const int xcd = g & 7, slot = g >> 3;        // slot in [0,128)
  const int grp = slot & 7, tn = slot >> 3;    // tn in [0,16), slowest
  const int b  = xcd >> 1;                     // batch in [0,4)
  const int ty = (grp << 1) | (xcd & 1);       // strip in [0,16)
  gemm256_nt<4>(qb + ((size_t)b * SEQ + ty * 256) * DIM,
                kb + ((size_t)b * SEQ + tn * 256) * DIM,
                DIM, DIM, DIM, lds, acc);

  const int tid = threadIdx.x, lane = tid & 63, wid = tid >> 6;
  const int wr = wid >> 2, wc = wid & 3;
  const int lr = lane & 15, q = lane >> 4;

  float rs[8][4];
#pragma unroll
  for (int i = 0; i < 8; ++i)
#pragma unroll
    for (int r = 0; r < 4; ++r) rs[i][r] = 0.f;

#pragma unroll
  for (int i = 0; i < 8; ++i)
#pragma unroll
    for (int j = 0; j < 4; ++j) {
      const int col = wc * 64 + j * 16 + lr;
#pragma unroll
      for (int r = 0; r < 4; ++r) {
        const int row = wr * 128 + i * 16 + (q << 2) + r;
        const float e = __expf(acc[i][j][r]);
        lds[row * 256 + (((col >> 3) ^ (((row >> 2) & 3) << 1)) << 3) + (col & 7)] = f2bf(e);
        rs[i][r] += e;
      }
    }

  float* lp = lpart + (size_t)(tn * 4 + wc) * NTOK;
  const int lbase = b * SEQ + ty * 256 + wr * 128 + (q << 2);
#pragma unroll
  for (int i = 0; i < 8; ++i)
#pragma unroll
    for (int r = 0; r < 4; ++r) {
      float v = rs[i][r];
      v += __shfl_xor(v, 1); v += __shfl_xor(v, 2);
      v += __shfl_xor(v, 4); v += __shfl_xor(v, 8);
      if (lr == 0) lp[lbase + i * 16 + r] = v;
    }
  __syncthreads();
  unsigned short* Sb = S + (size_t)b * SEQ * SEQ;
  const int rL = tid >> 5, cc = tid & 31;
#pragma unroll
  for (int pp = 0; pp < 16; ++pp) {
    const int row = pp * 16 + rL;
    const int pos = cc ^ (((row >> 2) & 3) << 1);
    *(uint4*)(Sb + (size_t)(ty * 256 + row) * SEQ + tn * 256 + cc * 8) =
        *(const uint4*)(lds + row * 256 + pos * 8);
  }
}

// ---- kernel 2b: fold 64 partials per row -> reciprocal row sum ----
__global__ __launch_bounds__(256) void k_lred(const float* __restrict__ lpart,
                                              float* __restrict__ lsum) {
  const int tid = threadIdx.x;
  const int row = blockIdx.x * 64 + (tid >> 2);
  const int part = tid & 3;
  float s = 0.f;
#pragma unroll
  for (int t = 0; t < 16; ++t)
    s += lpart[(size_t)(part * 16 + t) * NTOK + row];
  s += __shfl_xor(s, 1);
  s += __shfl_xor(s, 2);
  if (part == 0) lsum[row] = 1.0f / s;
}

// ---- kernel 3: out[b] = (P'[b] @ vT[b]^T) * lsum ---- (nt reverted: R13)
// Mapping already batch-per-XCD; P strips stream with 2-block L2 pairing.
__global__ __launch_bounds__(512, 2) void k_pv(
    const unsigned short* __restrict__ P, const unsigned short* __restrict__ vT,
    const float* __restrict__ lsum, float* __restrict__ out)
{
  __shared__ unsigned short lds[57344];        // 112 KB
  f32x4 acc[8][3];
  const int g = blockIdx.x;                    // flat grid 256
  const int xcd = g & 7, s = g >> 3;           // s in [0,32)
  const int combo = xcd * 2 + (s & 1);         // [0,16)
  const int b = combo >> 2, tn = combo & 3;
  const int tm = s >> 1;                       // [0,16)
  gemm256_nt<3>(P + (size_t)b * SEQ * SEQ + (size_t)(tm * 256) * SEQ,
                vT + (size_t)b * DIM * SEQ + (size_t)(tn * 192) * SEQ,
                SEQ, SEQ, SEQ, lds, acc);

  const int tid = threadIdx.x, lane = tid & 63, wid = tid >> 6;
  const int wr = wid >> 2, wc = wid & 3;
  const int lr = lane & 15, q = lane >> 4;
  const int lbase = b * SEQ + tm * 256 + wr * 128 + (q << 2);
  float inv[8][4];
#pragma unroll
  for (int i = 0; i < 8; ++i)
#pragma unroll
    for (int r = 0; r < 4; ++r) inv[i][r] = lsum[lbase + i * 16 + r];
  float* ob = out + (size_t)b * SEQ * DIM;
#pragma unroll
  for (int i = 0; i < 8; ++i)
#pragma unroll
    for (int j = 0; j < 3; ++j) {
      const int col  = tn * 192 + wc * 48 + j * 16 + lr;
      const int row0 = tm * 256 + wr * 128 + i * 16 + (q << 2);
#pragma unroll
      for (int r = 0; r < 4; ++r)
        ob[(size_t)(row0 + r) * DIM + col] = acc[i][j][r] * inv[i][r];
    }
}

extern "C" void kernel_launch(void* const* d_in, const int* in_sizes, int n_in,
                              void* d_out, int out_size, void* d_ws, size_t ws_size,
                              hipStream_t stream) {
  const float* x    = (const float*)d_in[0];
  const float* W    = (const float*)d_in[1];
  const float* bias = (const float*)d_in[2];
  float* out = (float*)d_out;

  char* w = (char*)d_ws;
  unsigned short* x_bf = (unsigned short*)(w);
  unsigned short* Wt   = (unsigned short*)(w + 25165824);
  unsigned short* qb   = (unsigned short*)(w + 28704768);
  unsigned short* kb   = (unsigned short*)(w + 53870592);
  unsigned short* vT   = (unsigned short*)(w + 79036416);
  unsigned short* S    = (unsigned short*)(w + 104202240);
  // lpart (4 MB) + lsum (64 KB) reuse the x_bf region (dead after k_qkv)
  float* lpart = (float*)(w);
  float* lsum  = (float*)(w + 4194304);

  k_cvt      <<<12288, 256, 0, stream>>>(x, x_bf);
  k_transpose<<<dim3(72, 24), 256, 0, stream>>>(W, Wt);
  k_qkv      <<<2304, 256, 0, stream>>>(x_bf, Wt, bias, qb, kb, vT);
  k_scores   <<<1024, 512, 0, stream>>>(qb, kb, S, lpart);
  k_lred     <<<256, 256, 0, stream>>>(lpart, lsum);
  k_pv       <<<256, 512, 0, stream>>>(S, vT, lsum, out);
}

// Round 7
// 421.017 us; speedup vs baseline: 1.0388x; 1.0124x over previous
//
#include <hip/hip_runtime.h>
#include <stdint.h>

typedef __attribute__((ext_vector_type(8))) short short8;
typedef __attribute__((ext_vector_type(4))) float f32x4;

#define DIM 768
#define H3 2304
#define SEQ 4096
#define NTOK 16384

__device__ __forceinline__ unsigned short f2bf(float f) {
  union { float f; uint32_t u; } c; c.f = f;
  uint32_t u = c.u;
  u += 0x7FFFu + ((u >> 16) & 1u);   // RNE; inputs are finite
  return (unsigned short)(u >> 16);
}

__device__ __forceinline__ void async_cp16(const void* g, void* l) {
  // global -> LDS direct, 16B per lane. LDS dest must be waveBase + lane*16 (it is).
  __builtin_amdgcn_global_load_lds(
      (__attribute__((address_space(1))) void*)(void*)g,
      (__attribute__((address_space(3))) void*)l, 16, 0, 0);
}

#define MEMFENCE() asm volatile("" ::: "memory")
#define BARRIER() do { MEMFENCE(); __builtin_amdgcn_s_barrier(); MEMFENCE(); } while (0)
#define WAIT_VMCNT(n) asm volatile("s_waitcnt vmcnt(" #n ")" ::: "memory")

// Counted LDS gate: wait until <=N ds_reads outstanding, then pin the
// scheduler (rule #18: MFMAs otherwise hoist past inline-asm waitcnt).
template <int N>
__device__ __forceinline__ void wait_lgk() {
  asm volatile("s_waitcnt lgkmcnt(%0)" :: "n"(N) : "memory");
  __builtin_amdgcn_sched_barrier(0);
}

// ---- legacy 128-tile NT GEMM core (kept for k_qkv only) ----
template<int JN>
__device__ __forceinline__ void gemm_nt64_t(
    const unsigned short* __restrict__ A, const unsigned short* __restrict__ B,
    int K, int ldA, int ldB,
    unsigned short* As, unsigned short* Bs, f32x4 acc[4][JN])
{
  const int tid = threadIdx.x, lane = tid & 63, wid = tid >> 6;
  const int wm = (wid & 1) << 6, wn = (wid >> 1) * (JN * 16);
  const int lr = lane & 15, q = lane >> 4;

#pragma unroll
  for (int i = 0; i < 4; ++i)
#pragma unroll
    for (int j = 0; j < JN; ++j)
      acc[i][j] = (f32x4){0.f, 0.f, 0.f, 0.f};

  const unsigned short* gA[4];
  const unsigned short* gB[JN];
#pragma unroll
  for (int t = 0; t < 4; ++t) {
    const int c = tid + 256 * t;
    const int row = c >> 3, sc = c & 7;
    gA[t] = A + (size_t)row * ldA + (((sc ^ (row & 7)) << 3));
  }
#pragma unroll
  for (int t = 0; t < JN; ++t) {
    const int c = tid + 256 * t;
    const int row = c >> 3, sc = c & 7;
    gB[t] = B + (size_t)row * ldB + (((sc ^ (row & 7)) << 3));
  }

  for (int k0 = 0; k0 < K; k0 += 64) {
#pragma unroll
    for (int t = 0; t < 4; ++t)
      async_cp16(gA[t] + k0, As + (tid + 256 * t) * 8);
#pragma unroll
    for (int t = 0; t < JN; ++t)
      async_cp16(gB[t] + k0, Bs + (tid + 256 * t) * 8);
    __syncthreads();

    short8 af[4][2], bfr[JN][2];
#pragma unroll
    for (int i = 0; i < 4; ++i) {
      const int ra = wm + i * 16 + lr;
#pragma unroll
      for (int s2 = 0; s2 < 2; ++s2)
        af[i][s2] = *(const short8*)(As + ra * 64 + (((s2 * 4 + q) ^ (ra & 7)) << 3));
    }
#pragma unroll
    for (int j = 0; j < JN; ++j) {
      const int rb = wn + j * 16 + lr;
#pragma unroll
      for (int s2 = 0; s2 < 2; ++s2)
        bfr[j][s2] = *(const short8*)(Bs + rb * 64 + (((s2 * 4 + q) ^ (rb & 7)) << 3));
    }
#pragma unroll
    for (int s2 = 0; s2 < 2; ++s2)
#pragma unroll
      for (int i = 0; i < 4; ++i)
#pragma unroll
        for (int j = 0; j < JN; ++j)
          acc[i][j] = __builtin_amdgcn_mfma_f32_16x16x32_bf16(af[i][s2], bfr[j][s2], acc[i][j], 0, 0, 0);
    __syncthreads();
  }
}

// ---- R15: 256-wide counted-lgkmcnt pipelined NT GEMM core ----
// History: R11 measured 4-phase core at MfmaUtil 31% (2480 MFMA cyc vs 6860
// cyc/K-tile). R14 halved FETCH (73.8 MB, L2 thrash gone) but dur flat ->
// stall is the per-phase [barrier; lgkmcnt(0); MFMA; barrier] structure:
// each phase's ds_reads + LDS BW + latency fully exposed between MFMA
// clusters, 4x per K-tile, 8 barriers/K-tile, no TLP (2 lockstep waves/SIMD).
// R15: fragment loads issued one phase ahead, counted lgkmcnt gates (T4),
// 2 barriers/K-tile. Per tile t (NB = JN-2):
//   S1: stage B(t+1) (JN gloads)          [Bsn last read ph3/4(t-1), synced
//   R1: fa0 x8 + fbj(h0,j01) x2            by opening barrier]
//   R2: fbk(h0,j2..) xNB
//   lgkm(NB)  -> MFMA1 (fa0 x fbj)        [only gate not MFMA-covered]
//   R3: fa1 x8 + fbj(h1) x2  (fbj WAR-safe: SSA renaming)
//   lgkm(10)  -> MFMA2 (fa0 x fbk)
//   R4: fbk(h1) xNB
//   lgkm(NB)  -> MFMA3 (fa1 x fbj)
//   BARRIER   [gate3 passed by all waves => all A-reads drained]
//   S2: stage A(t+2) into As[t&1] (in-place A pipeline, same as R10)
//   lgkm(0)   -> MFMA4 (fa1 x fbk)
//   vmcnt(4)  [retires A(t+1)+B(t+1); leaves A(t+2) in flight]
//   BARRIER   [= open(t+1)]
// Accumulation order per acc[i][j] identical to R10 (h0 then h1 per tile).
template<int JN>
__device__ __forceinline__ void gemm256_nt(
    const unsigned short* __restrict__ A, const unsigned short* __restrict__ B,
    int K, int ldA, int ldB, unsigned short* lds, f32x4 acc[8][JN])
{
  constexpr int NB = JN - 2;
  const int tid = threadIdx.x, lane = tid & 63, wid = tid >> 6;
  const int wr = wid >> 2, wc = wid & 3;
  const int lr = lane & 15, q = lane >> 4;

  unsigned short* const As0 = lds;
  unsigned short* const As1 = lds + 16384;
  unsigned short* const Bs0 = lds + 32768;
  unsigned short* const Bs1 = lds + 32768 + JN * 4096;

#pragma unroll
  for (int i = 0; i < 8; ++i)
#pragma unroll
    for (int j = 0; j < JN; ++j)
      acc[i][j] = (f32x4){0.f, 0.f, 0.f, 0.f};

  const unsigned short* gA[4];
  const unsigned short* gB[JN];
#pragma unroll
  for (int t = 0; t < 4; ++t) {
    const int c = tid + 512 * t, row = c >> 3, sc = c & 7;
    gA[t] = A + (size_t)row * ldA + ((sc ^ (row & 7)) << 3);
  }
#pragma unroll
  for (int t = 0; t < JN; ++t) {
    const int c = tid + 512 * t, row = c >> 3, sc = c & 7;
    gB[t] = B + (size_t)row * ldB + ((sc ^ (row & 7)) << 3);
  }

  // Loop-invariant LDS element offsets (keeps swizzle math out of the
  // per-phase dependency chain).
  unsigned offA[8][2], offB[JN][2];
#pragma unroll
  for (int i = 0; i < 8; ++i) {
    const int ra = wr * 128 + i * 16 + lr;
#pragma unroll
    for (int h = 0; h < 2; ++h)
      offA[i][h] = ra * 64 + (((h * 4 + q) ^ (ra & 7)) << 3);
  }
#pragma unroll
  for (int j = 0; j < JN; ++j) {
    const int rb = wc * (JN * 16) + j * 16 + lr;
#pragma unroll
    for (int h = 0; h < 2; ++h)
      offB[j][h] = rb * 64 + (((h * 4 + q) ^ (rb & 7)) << 3);
  }

  const int nt = K >> 6;

  // prologue: tile0 (A,B) -> buf0; tile1 A -> buf1. vmcnt(4): tile0 landed,
  // tile1's 4 A-loads stay in flight (steady-state ledger at tile open).
#pragma unroll
  for (int t = 0; t < 4; ++t) async_cp16(gA[t], As0 + (tid + 512 * t) * 8);
#pragma unroll
  for (int t = 0; t < JN; ++t) async_cp16(gB[t], Bs0 + (tid + 512 * t) * 8);
  const int k1 = (nt > 1) ? 64 : 0;
#pragma unroll
  for (int t = 0; t < 4; ++t) async_cp16(gA[t] + k1, As1 + (tid + 512 * t) * 8);
  WAIT_VMCNT(4);
  BARRIER();

#pragma unroll 2
  for (int t = 0; t < nt; ++t) {
    const int p = t & 1;
    const unsigned short* const Asp = p ? As1 : As0;
    const unsigned short* const Bsp = p ? Bs1 : Bs0;
    unsigned short* const Bsn = p ? Bs0 : Bs1;           // B stage: tile t+1
    unsigned short* const Asn = p ? As1 : As0;           // A stage: tile t+2 (same buf)
    const int kB = ((t + 1 < nt) ? t + 1 : nt - 1) << 6; // clamped tail re-load keeps
    const int kA = ((t + 2 < nt) ? t + 2 : nt - 1) << 6; // the vmcnt ledger uniform

    // S1: stage B(t+1)
#pragma unroll
    for (int u = 0; u < JN; ++u)
      async_cp16(gB[u] + kB, Bsn + (tid + 512 * u) * 8);

    short8 fa0[8], fa1[8], fbj[2], fbk[(NB > 0) ? NB : 1];
    // R1: A half0 + B half0 j=0,1
#pragma unroll
    for (int i = 0; i < 8; ++i) fa0[i] = *(const short8*)(Asp + offA[i][0]);
#pragma unroll
    for (int j = 0; j < 2; ++j) fbj[j] = *(const short8*)(Bsp + offB[j][0]);
    // R2: B half0 j=2..
#pragma unroll
    for (int j = 0; j < NB; ++j) fbk[j] = *(const short8*)(Bsp + offB[2 + j][0]);

    wait_lgk<NB>();                          // fa0, fbj ready (fbk may be in flight)
    __builtin_amdgcn_s_setprio(1);
#pragma unroll
    for (int i = 0; i < 8; ++i)
#pragma unroll
      for (int j = 0; j < 2; ++j)
        acc[i][j] = __builtin_amdgcn_mfma_f32_16x16x32_bf16(fa0[i], fbj[j], acc[i][j], 0, 0, 0);
    __builtin_amdgcn_s_setprio(0);

    // R3: A half1 + B half1 j=0,1 (issued under MFMA1/MFMA2 cover)
#pragma unroll
    for (int i = 0; i < 8; ++i) fa1[i] = *(const short8*)(Asp + offA[i][1]);
#pragma unroll
    for (int j = 0; j < 2; ++j) fbj[j] = *(const short8*)(Bsp + offB[j][1]);

    wait_lgk<10>();                          // retires R2 (fbk h0); R3 may fly
    __builtin_amdgcn_s_setprio(1);
#pragma unroll
    for (int i = 0; i < 8; ++i)
#pragma unroll
      for (int j = 0; j < NB; ++j)
        acc[i][2 + j] = __builtin_amdgcn_mfma_f32_16x16x32_bf16(fa0[i], fbk[j], acc[i][2 + j], 0, 0, 0);
    __builtin_amdgcn_s_setprio(0);

    // R4: B half1 j=2..
#pragma unroll
    for (int j = 0; j < NB; ++j) fbk[j] = *(const short8*)(Bsp + offB[2 + j][1]);

    wait_lgk<NB>();                          // retires R3 (fa1, fbj h1)
    __builtin_amdgcn_s_setprio(1);
#pragma unroll
    for (int i = 0; i < 8; ++i)
#pragma unroll
      for (int j = 0; j < 2; ++j)
        acc[i][j] = __builtin_amdgcn_mfma_f32_16x16x32_bf16(fa1[i], fbj[j], acc[i][j], 0, 0, 0);
    __builtin_amdgcn_s_setprio(0);

    BARRIER();  // all waves passed gate3 => every A-read of this tile drained
    // S2: stage A(t+2) in-place into As[t&1]
#pragma unroll
    for (int u = 0; u < 4; ++u)
      async_cp16(gA[u] + kA, Asn + (tid + 512 * u) * 8);

    wait_lgk<0>();                           // retires R4 (fbk h1)
    __builtin_amdgcn_s_setprio(1);
#pragma unroll
    for (int i = 0; i < 8; ++i)
#pragma unroll
      for (int j = 0; j < NB; ++j)
        acc[i][2 + j] = __builtin_amdgcn_mfma_f32_16x16x32_bf16(fa1[i], fbk[j], acc[i][2 + j], 0, 0, 0);
    __builtin_amdgcn_s_setprio(0);

    WAIT_VMCNT(4);                           // A(t+1)+B(t+1) landed; A(t+2) flies
    BARRIER();                               // = open(t+1)
  }
  // drain clamped tail prefetches before LDS reuse / kernel exit.
  WAIT_VMCNT(0);
  BARRIER();
}

// ---- kernel 0a: fp32 -> bf16 bulk convert (x) ----
__global__ __launch_bounds__(256) void k_cvt(const float* __restrict__ in,
                                             unsigned short* __restrict__ o) {
  int i = blockIdx.x * 256 + threadIdx.x;
  float4 f = ((const float4*)in)[i];
  ushort4 u;
  u.x = f2bf(f.x); u.y = f2bf(f.y); u.z = f2bf(f.z); u.w = f2bf(f.w);
  ((ushort4*)o)[i] = u;
}

// ---- kernel 0b: W [768,2304] fp32 -> Wt [2304,768] bf16 ----
__global__ __launch_bounds__(256) void k_transpose(const float* __restrict__ W,
                                                   unsigned short* __restrict__ Wt) {
  __shared__ float tile[32][33];
  const int bc = blockIdx.x * 32;
  const int br = blockIdx.y * 32;
  const int tx = threadIdx.x & 31, ty = threadIdx.x >> 5;
#pragma unroll
  for (int i = 0; i < 32; i += 8)
    tile[ty + i][tx] = W[(size_t)(br + ty + i) * H3 + bc + tx];
  __syncthreads();
#pragma unroll
  for (int i = 0; i < 32; i += 8)
    Wt[(size_t)(bc + ty + i) * DIM + br + tx] = f2bf(tile[tx][ty + i]);
}

// ---- kernel 1: qkv = x @ Wt^T + b ; q scaled, k plain, v transposed ----
__global__ __launch_bounds__(256) void k_qkv(
    const unsigned short* __restrict__ xbf, const unsigned short* __restrict__ Wt,
    const float* __restrict__ bias,
    unsigned short* __restrict__ qb, unsigned short* __restrict__ kb,
    unsigned short* __restrict__ vT)
{
  __shared__ unsigned short As[128 * 64];
  __shared__ unsigned short Bs[128 * 64];
  f32x4 acc[4][4];
  const int g = blockIdx.x;
  const int xcd = g & 7, slot = g >> 3;        // slot in [0,288)
  const int tn = slot % 18, grp = slot / 18;   // grp in [0,16)
  const int tm = xcd + 8 * grp;                // row-strip in [0,128)
  gemm_nt64_t<4>(xbf + (size_t)(tm * 128) * DIM, Wt + (size_t)(tn * 128) * DIM,
                 DIM, DIM, DIM, As, Bs, acc);

  const int tid = threadIdx.x, lane = tid & 63, wid = tid >> 6;
  const int wm = (wid & 1) << 6, wn = (wid >> 1) << 6;
  const float scale = 0.036084391824351615f;  // 1/sqrt(768)
#pragma unroll
  for (int i = 0; i < 4; ++i) {
#pragma unroll
    for (int j = 0; j < 4; ++j) {
      const int col  = tn * 128 + wn + j * 16 + (lane & 15);
      const int row0 = tm * 128 + wm + i * 16 + ((lane >> 4) << 2);
      const float bc = bias[col];
#pragma unroll
      for (int r = 0; r < 4; ++r) {
        const int row = row0 + r;
        const float v = acc[i][j][r] + bc;
        if (col < 768) {
          qb[(size_t)row * DIM + col] = f2bf(v * scale);
        } else if (col < 1536) {
          kb[(size_t)row * DIM + (col - 768)] = f2bf(v);
        } else {
          const int b = row >> 12, n = row & 4095;
          vT[((size_t)b * DIM + (col - 1536)) * SEQ + n] = f2bf(v);
        }
      }
    }
  }
}

// ---- kernel 2: P'[b] = exp(q@k^T), batch-per-XCD map (R14) + R15 core ----
__global__ __launch_bounds__(512, 2) void k_scores(
    const unsigned short* __restrict__ qb, const unsigned short* __restrict__ kb,
    unsigned short* __restrict__ S, float* __restrict__ lpart)
{
  __shared__ unsigned short lds[65536];        // 128 KB
  f32x4 acc[8][4];
  const int g = blockIdx.x;
  const int xcd = g & 7, slot = g >> 3;        // slot in [0,128)
  const int grp = slot & 7, tn = slot >> 3;    // tn in [0,16), slowest
  const int b  = xcd >> 1;                     // batch in [0,4)
  const int ty = (grp << 1) | (xcd & 1);       // strip in [0,16)
  gemm256_nt<4>(qb + ((size_t)b * SEQ + ty * 256) * DIM,
                kb + ((size_t)b * SEQ + tn * 256) * DIM,
                DIM, DIM, DIM, lds, acc);

  const int tid = threadIdx.x, lane = tid & 63, wid = tid >> 6;
  const int wr = wid >> 2, wc = wid & 3;
  const int lr = lane & 15, q = lane >> 4;

  float rs[8][4];
#pragma unroll
  for (int i = 0; i < 8; ++i)
#pragma unroll
    for (int r = 0; r < 4; ++r) rs[i][r] = 0.f;

#pragma unroll
  for (int i = 0; i < 8; ++i)
#pragma unroll
    for (int j = 0; j < 4; ++j) {
      const int col = wc * 64 + j * 16 + lr;
#pragma unroll
      for (int r = 0; r < 4; ++r) {
        const int row = wr * 128 + i * 16 + (q << 2) + r;
        const float e = __expf(acc[i][j][r]);
        lds[row * 256 + (((col >> 3) ^ (((row >> 2) & 3) << 1)) << 3) + (col & 7)] = f2bf(e);
        rs[i][r] += e;
      }
    }

  float* lp = lpart + (size_t)(tn * 4 + wc) * NTOK;
  const int lbase = b * SEQ + ty * 256 + wr * 128 + (q << 2);
#pragma unroll
  for (int i = 0; i < 8; ++i)
#pragma unroll
    for (int r = 0; r < 4; ++r) {
      float v = rs[i][r];
      v += __shfl_xor(v, 1); v += __shfl_xor(v, 2);
      v += __shfl_xor(v, 4); v += __shfl_xor(v, 8);
      if (lr == 0) lp[lbase + i * 16 + r] = v;
    }
  __syncthreads();
  unsigned short* Sb = S + (size_t)b * SEQ * SEQ;
  const int rL = tid >> 5, cc = tid & 31;
#pragma unroll
  for (int pp = 0; pp < 16; ++pp) {
    const int row = pp * 16 + rL;
    const int pos = cc ^ (((row >> 2) & 3) << 1);
    *(uint4*)(Sb + (size_t)(ty * 256 + row) * SEQ + tn * 256 + cc * 8) =
        *(const uint4*)(lds + row * 256 + pos * 8);
  }
}

// ---- kernel 2b: fold 64 partials per row -> reciprocal row sum ----
__global__ __launch_bounds__(256) void k_lred(const float* __restrict__ lpart,
                                              float* __restrict__ lsum) {
  const int tid = threadIdx.x;
  const int row = blockIdx.x * 64 + (tid >> 2);
  const int part = tid & 3;
  float s = 0.f;
#pragma unroll
  for (int t = 0; t < 16; ++t)
    s += lpart[(size_t)(part * 16 + t) * NTOK + row];
  s += __shfl_xor(s, 1);
  s += __shfl_xor(s, 2);
  if (part == 0) lsum[row] = 1.0f / s;
}

// ---- kernel 3: out[b] = (P'[b] @ vT[b]^T) * lsum, R15 core ----
__global__ __launch_bounds__(512, 2) void k_pv(
    const unsigned short* __restrict__ P, const unsigned short* __restrict__ vT,
    const float* __restrict__ lsum, float* __restrict__ out)
{
  __shared__ unsigned short lds[57344];        // 112 KB
  f32x4 acc[8][3];
  const int g = blockIdx.x;                    // flat grid 256
  const int xcd = g & 7, s = g >> 3;           // s in [0,32)
  const int combo = xcd * 2 + (s & 1);         // [0,16)
  const int b = combo >> 2, tn = combo & 3;
  const int tm = s >> 1;                       // [0,16)
  gemm256_nt<3>(P + (size_t)b * SEQ * SEQ + (size_t)(tm * 256) * SEQ,
                vT + (size_t)b * DIM * SEQ + (size_t)(tn * 192) * SEQ,
                SEQ, SEQ, SEQ, lds, acc);

  const int tid = threadIdx.x, lane = tid & 63, wid = tid >> 6;
  const int wr = wid >> 2, wc = wid & 3;
  const int lr = lane & 15, q = lane >> 4;
  const int lbase = b * SEQ + tm * 256 + wr * 128 + (q << 2);
  float inv[8][4];
#pragma unroll
  for (int i = 0; i < 8; ++i)
#pragma unroll
    for (int r = 0; r < 4; ++r) inv[i][r] = lsum[lbase + i * 16 + r];
  float* ob = out + (size_t)b * SEQ * DIM;
#pragma unroll
  for (int i = 0; i < 8; ++i)
#pragma unroll
    for (int j = 0; j < 3; ++j) {
      const int col  = tn * 192 + wc * 48 + j * 16 + lr;
      const int row0 = tm * 256 + wr * 128 + i * 16 + (q << 2);
#pragma unroll
      for (int r = 0; r < 4; ++r)
        ob[(size_t)(row0 + r) * DIM + col] = acc[i][j][r] * inv[i][r];
    }
}

extern "C" void kernel_launch(void* const* d_in, const int* in_sizes, int n_in,
                              void* d_out, int out_size, void* d_ws, size_t ws_size,
                              hipStream_t stream) {
  const float* x    = (const float*)d_in[0];
  const float* W    = (const float*)d_in[1];
  const float* bias = (const float*)d_in[2];
  float* out = (float*)d_out;

  char* w = (char*)d_ws;
  unsigned short* x_bf = (unsigned short*)(w);
  unsigned short* Wt   = (unsigned short*)(w + 25165824);
  unsigned short* qb   = (unsigned short*)(w + 28704768);
  unsigned short* kb   = (unsigned short*)(w + 53870592);
  unsigned short* vT   = (unsigned short*)(w + 79036416);
  unsigned short* S    = (unsigned short*)(w + 104202240);
  // lpart (4 MB) + lsum (64 KB) reuse the x_bf region (dead after k_qkv)
  float* lpart = (float*)(w);
  float* lsum  = (float*)(w + 4194304);

  k_cvt      <<<12288, 256, 0, stream>>>(x, x_bf);
  k_transpose<<<dim3(72, 24), 256, 0, stream>>>(W, Wt);
  k_qkv      <<<2304, 256, 0, stream>>>(x_bf, Wt, bias, qb, kb, vT);
  k_scores   <<<1024, 512, 0, stream>>>(qb, kb, S, lpart);
  k_lred     <<<256, 256, 0, stream>>>(lpart, lsum);
  k_pv       <<<256, 512, 0, stream>>>(S, vT, lsum, out);
}